// Round 6
// baseline (532.631 us; speedup 1.0000x reference)
//
#include <hip/hip_runtime.h>
#include <cmath>

#define NMEM 65536
#define MSZ  256
#define EPSC 1e-8f
#define GRID_BIG 1024         // big-pass blocks; 64 rows each, 16/wave, 2 pipelined batches of 8

// ---- workspace layout (float offsets) ----
enum : int {
    OFF_GATES = 0,        // 4096
    OFF_CTRL  = 4096,     // 1024
    OFF_OW    = 5120,     // 4*774 = 3096
    OFF_ORR   = 8216,     // 4*262 = 1048
    OFF_K     = 9264,     // 8*256
    OFF_E     = 11312,    // 4*256
    OFF_A     = 12336,    // 4*256
    OFF_SCAL  = 13360,    // 8*8: [knorm, beta, g, s0, s1, s2, gamma, -]
    OFF_READS = 13424,    // 4*256 (atomic accumulated)
    OFF_PAIRS = 14448,    // 1024*2 online-softmax partials
    OFF_TPART = 16496,    // 256 sharpen-sum partials
    OFF_SIM   = 16752,    // 65536
    OFF_WSH   = 82288,    // 65536
    OFF_NSQ   = 147824,   // 65536 (post-update row norm^2; optional)
    WS_FLOATS = 213360
};

__device__ __forceinline__ float wave_sum(float v) {
#pragma unroll
    for (int off = 32; off > 0; off >>= 1) v += __shfl_xor(v, off);
    return v;
}
__device__ __forceinline__ float sigmoidf_(float x) { return 1.f / (1.f + expf(-x)); }
__device__ __forceinline__ float softplusf_(float x) { return (x > 20.f) ? x : log1pf(expf(x)); }
__device__ __forceinline__ void pair_merge(float& m, float& s, float m2, float s2) {
    if (m2 > m) { s = s * expf(m - m2) + s2; m = m2; }
    else        { s += s2 * expf(m2 - m); }
}
__device__ __forceinline__ float dot4(float4 a, float4 b) {
    return a.x * b.x + a.y * b.y + a.z * b.z + a.w * b.w;
}

// block-level merge of per-wave (m,s) partials -> PAIRS[blockIdx]
__device__ __forceinline__ void block_pair_out(float m, float s, float* ws,
                                               int t, int lane, int wid) {
    __shared__ float sm[4], ss2[4];
    if (lane == 0) { sm[wid] = m; ss2[wid] = s; }
    __syncthreads();
    if (t == 0) {
        float M = sm[0], S = ss2[0];
#pragma unroll
        for (int i = 1; i < 4; ++i) pair_merge(M, S, sm[i], ss2[i]);
        ws[OFF_PAIRS + blockIdx.x * 2]     = M;
        ws[OFF_PAIRS + blockIdx.x * 2 + 1] = S;
    }
}

// all-lane batched reduce of 8 values (6 stages, 8-way ILP)
#define BFLY8(arr)                                            \
    _Pragma("unroll")                                         \
    for (int off = 32; off > 0; off >>= 1) {                  \
        _Pragma("unroll")                                     \
        for (int r = 0; r < 8; ++r) arr[r] += __shfl_xor(arr[r], off); \
    }

// per-batch epilogue: sims from reduced d/q, per-lane sim store, local (m,s)
#define SIM_EPILOGUE(d, q, n0, mb, sb)                        \
    {                                                         \
        float z8[8];                                          \
        _Pragma("unroll")                                     \
        for (int r = 0; r < 8; ++r) {                         \
            const float sim = d[r] / (sqrtf(q[r]) * knorm + EPSC); \
            if (lane == r) ws[OFF_SIM + (n0) + r] = sim;      \
            z8[r] = beta * sim;                               \
        }                                                     \
        mb = z8[0];                                           \
        _Pragma("unroll")                                     \
        for (int r = 1; r < 8; ++r) mb = fmaxf(mb, z8[r]);    \
        sb = 0.f;                                             \
        _Pragma("unroll")                                     \
        for (int r = 0; r < 8; ++r) sb += expf(z8[r] - mb);   \
    }

// ---- LSTM gates: one wave per output row (4096 rows) ----
__global__ __launch_bounds__(256) void k_gates(
    const float* __restrict__ x, const float* __restrict__ prev_reads,
    const float* __restrict__ prev_h, const float* __restrict__ W_ih,
    const float* __restrict__ W_hh, const float* __restrict__ b_lstm,
    float* __restrict__ ws)
{
    const int row  = (blockIdx.x * 256 + threadIdx.x) >> 6;
    const int lane = threadIdx.x & 63;
    const float* wrow = W_ih + (size_t)row * 3072;
    float acc = 0.f;
#pragma unroll
    for (int j = lane * 4; j < 3072; j += 256) {
        float4 w4 = *(const float4*)(wrow + j);
        float4 v4 = (j < 2048) ? *(const float4*)(x + j)
                               : *(const float4*)(prev_reads + (j - 2048));
        acc += dot4(w4, v4);
    }
    const float* hrow = W_hh + (size_t)row * 1024;
#pragma unroll
    for (int j = lane * 4; j < 1024; j += 256) {
        acc += dot4(*(const float4*)(hrow + j), *(const float4*)(prev_h + j));
    }
    acc = wave_sum(acc);
    if (lane == 0) ws[OFF_GATES + row] = acc + b_lstm[row];
}

// ---- LSTM cell state -> ctrl ----
__global__ void k_cell(const float* __restrict__ prev_c, float* __restrict__ ws) {
    const int j = blockIdx.x * blockDim.x + threadIdx.x;
    if (j >= 1024) return;
    const float ig = ws[OFF_GATES + j];
    const float fg = ws[OFF_GATES + 1024 + j];
    const float gg = ws[OFF_GATES + 2048 + j];
    ws[OFF_CTRL + j] = sigmoidf_(fg) * prev_c[j] + sigmoidf_(ig) * tanhf(gg);
}

// ---- head FC outputs: 3096 write rows + 1048 read rows, wave per row ----
__global__ __launch_bounds__(256) void k_headfc(
    const float* __restrict__ Ww, const float* __restrict__ bw,
    const float* __restrict__ Wr, const float* __restrict__ br,
    float* __restrict__ ws)
{
    const int gwv  = (blockIdx.x * 256 + threadIdx.x) >> 6;
    const int lane = threadIdx.x & 63;
    const float* wrow; float bias; int dst;
    if (gwv < 3096) { wrow = Ww + (size_t)gwv * 1024; bias = bw[gwv]; dst = OFF_OW + gwv; }
    else { const int rr = gwv - 3096; wrow = Wr + (size_t)rr * 1024; bias = br[rr]; dst = OFF_ORR + rr; }
    const float* ctrl = ws + OFF_CTRL;
    float acc = 0.f;
#pragma unroll
    for (int j = lane * 4; j < 1024; j += 256) {
        acc += dot4(*(const float4*)(wrow + j), *(const float4*)(ctrl + j));
    }
    acc = wave_sum(acc);
    if (lane == 0) ws[dst] = acc + bias;
}

// ---- per-address params (+ zero READS): block p handles address p (0..7) ----
__global__ __launch_bounds__(256) void k_params(float* __restrict__ ws) {
    const int p = blockIdx.x, t = threadIdx.x;
    const float* o = (p < 4) ? (ws + OFF_OW + p * 774) : (ws + OFF_ORR + (p - 4) * 262);
    const float kj = tanhf(o[t]);
    ws[OFF_K + p * 256 + t] = kj;
    float ssq = wave_sum(kj * kj);
    __shared__ float red[4];
    if ((t & 63) == 0) red[t >> 6] = ssq;
    __syncthreads();
    if (t == 0) {
        float* sc = ws + OFF_SCAL + p * 8;
        sc[0] = sqrtf(red[0] + red[1] + red[2] + red[3]);
        sc[1] = softplusf_(o[256]);
        sc[2] = sigmoidf_(o[257]);
        const float a0 = o[258], a1 = o[259], a2 = o[260];
        const float mm = fmaxf(a0, fmaxf(a1, a2));
        const float e0 = expf(a0 - mm), e1 = expf(a1 - mm), e2 = expf(a2 - mm);
        const float inv = 1.f / (e0 + e1 + e2);
        sc[3] = e0 * inv; sc[4] = e1 * inv; sc[5] = e2 * inv;
        sc[6] = 1.f + softplusf_(o[261]);
    }
    if (p < 4) {
        ws[OFF_E + p * 256 + t] = sigmoidf_(o[262 + t]);
        ws[OFF_A + p * 256 + t] = tanhf(o[518 + t]);
        ws[OFF_READS + p * 256 + t] = 0.f;   // init accumulators (ws is poisoned)
    }
}

// ---- cosine-sim pass: 1024 blocks, 16 rows/wave, 2 pipelined batches ----
__global__ __launch_bounds__(256) void k_sim(const float* __restrict__ mem,
                                             float* __restrict__ ws, int p)
{
    const int t = threadIdx.x, lane = t & 63, wid = t >> 6;
    const float4 k4   = *(const float4*)(ws + OFF_K + p * 256 + lane * 4);
    const float knorm = ws[OFF_SCAL + p * 8 + 0];
    const float beta  = ws[OFF_SCAL + p * 8 + 1];
    const int nA = blockIdx.x * 64 + wid * 16;
    const int nB = nA + 8;
    float4 vA[8], vB[8];
#pragma unroll
    for (int r = 0; r < 8; ++r) vA[r] = *(const float4*)(mem + (size_t)(nA + r) * MSZ + lane * 4);
#pragma unroll
    for (int r = 0; r < 8; ++r) vB[r] = *(const float4*)(mem + (size_t)(nB + r) * MSZ + lane * 4);
    float dA[8], qA[8];
#pragma unroll
    for (int r = 0; r < 8; ++r) { dA[r] = dot4(vA[r], k4); qA[r] = dot4(vA[r], vA[r]); }
    BFLY8(dA); BFLY8(qA);
    float mA, sA; SIM_EPILOGUE(dA, qA, nA, mA, sA);
    float dB[8], qB[8];
#pragma unroll
    for (int r = 0; r < 8; ++r) { dB[r] = dot4(vB[r], k4); qB[r] = dot4(vB[r], vB[r]); }
    BFLY8(dB); BFLY8(qB);
    float mB, sB; SIM_EPILOGUE(dB, qB, nB, mB, sB);
    pair_merge(mA, sA, mB, sB);
    block_pair_out(mA, sA, ws, t, lane, wid);
}

// ---- softmax + interpolate + shift + sharpen: 1 element per thread ----
__global__ __launch_bounds__(256) void k_smax(const float* __restrict__ prev_w,
                                              float* __restrict__ ws, int p)
{
    const int t = threadIdx.x;
    float m = ws[OFF_PAIRS + 2 * t], s = ws[OFF_PAIRS + 2 * t + 1];
#pragma unroll
    for (int b = 1; b < 4; ++b)
        pair_merge(m, s, ws[OFF_PAIRS + 2 * (t + 256 * b)], ws[OFF_PAIRS + 2 * (t + 256 * b) + 1]);
    __shared__ float sm[256], ss[256];
    sm[t] = m; ss[t] = s;
    __syncthreads();
    for (int str = 128; str > 0; str >>= 1) {
        if (t < str) {
            float mm = sm[t], sss = ss[t];
            pair_merge(mm, sss, sm[t + str], ss[t + str]);
            sm[t] = mm; ss[t] = sss;
        }
        __syncthreads();
    }
    const float M = sm[0], invS = 1.f / ss[0];
    const float* sc = ws + OFF_SCAL + p * 8;
    const float beta = sc[1], g = sc[2], s0 = sc[3], s1 = sc[4], s2 = sc[5], gam = sc[6];
    const float* sim = ws + OFF_SIM;
    const int n  = blockIdx.x * 256 + t;
    const int np = (n + 1) & (NMEM - 1);
    const int nm = (n + NMEM - 1) & (NMEM - 1);
    const float wg0 = g * expf(beta * sim[n]  - M) * invS + (1.f - g) * prev_w[n];
    const float wgp = g * expf(beta * sim[np] - M) * invS + (1.f - g) * prev_w[np];
    const float wgm = g * expf(beta * sim[nm] - M) * invS + (1.f - g) * prev_w[nm];
    const float wsn = s0 * wgp + s1 * wg0 + s2 * wgm;  // roll(-1), id, roll(+1)
    const float wsh = powf(fmaxf(wsn, 1e-12f), gam);
    ws[OFF_WSH + n] = wsh;
    float tsum = wave_sum(wsh);
    __shared__ float red[4];
    if ((t & 63) == 0) red[t >> 6] = tsum;
    __syncthreads();
    if (t == 0) ws[OFF_TPART + blockIdx.x] = red[0] + red[1] + red[2] + red[3];
}

__device__ __forceinline__ float load_invT(const float* __restrict__ ws,
                                           int t, int lane, int wid) {
    __shared__ float red[4];
    float v = wave_sum(ws[OFF_TPART + t]);   // 256 partials, one per thread
    if (lane == 0) red[wid] = v;
    __syncthreads();
    return 1.f / (red[0] + red[1] + red[2] + red[3] + EPSC);
}

// ---- memory update (write head hd) fused with read-address sim ----
__global__ __launch_bounds__(256) void k_update(float* __restrict__ mem,
                                                float* __restrict__ ws, int hd, int store_nsq)
{
    const int t = threadIdx.x, lane = t & 63, wid = t >> 6;
    const float invT = load_invT(ws, t, lane, wid);
    const int p = 4 + hd;
    const float4 k4   = *(const float4*)(ws + OFF_K + p * 256 + lane * 4);
    const float4 e4   = *(const float4*)(ws + OFF_E + hd * 256 + lane * 4);
    const float4 a4   = *(const float4*)(ws + OFF_A + hd * 256 + lane * 4);
    const float knorm = ws[OFF_SCAL + p * 8 + 0];
    const float beta  = ws[OFF_SCAL + p * 8 + 1];
    const int nA = blockIdx.x * 64 + wid * 16;
    const int nB = nA + 8;
    float wA[8], wB[8]; float4 vA[8], vB[8];
#pragma unroll
    for (int r = 0; r < 8; ++r) wA[r] = ws[OFF_WSH + nA + r];
#pragma unroll
    for (int r = 0; r < 8; ++r) wB[r] = ws[OFF_WSH + nB + r];
#pragma unroll
    for (int r = 0; r < 8; ++r) vA[r] = *(const float4*)(mem + (size_t)(nA + r) * MSZ + lane * 4);
#pragma unroll
    for (int r = 0; r < 8; ++r) vB[r] = *(const float4*)(mem + (size_t)(nB + r) * MSZ + lane * 4);
    // modify + store both batches first (stores in flight during reductions)
#pragma unroll
    for (int r = 0; r < 8; ++r) {
        const float w = wA[r] * invT;
        vA[r].x = vA[r].x * (1.f - w * e4.x) + w * a4.x;
        vA[r].y = vA[r].y * (1.f - w * e4.y) + w * a4.y;
        vA[r].z = vA[r].z * (1.f - w * e4.z) + w * a4.z;
        vA[r].w = vA[r].w * (1.f - w * e4.w) + w * a4.w;
        *(float4*)(mem + (size_t)(nA + r) * MSZ + lane * 4) = vA[r];
    }
#pragma unroll
    for (int r = 0; r < 8; ++r) {
        const float w = wB[r] * invT;
        vB[r].x = vB[r].x * (1.f - w * e4.x) + w * a4.x;
        vB[r].y = vB[r].y * (1.f - w * e4.y) + w * a4.y;
        vB[r].z = vB[r].z * (1.f - w * e4.z) + w * a4.z;
        vB[r].w = vB[r].w * (1.f - w * e4.w) + w * a4.w;
        *(float4*)(mem + (size_t)(nB + r) * MSZ + lane * 4) = vB[r];
    }
    float dA[8], qA[8];
#pragma unroll
    for (int r = 0; r < 8; ++r) { dA[r] = dot4(vA[r], k4); qA[r] = dot4(vA[r], vA[r]); }
    BFLY8(dA); BFLY8(qA);
    if (store_nsq) {
#pragma unroll
        for (int r = 0; r < 8; ++r) if (lane == r) ws[OFF_NSQ + nA + r] = qA[r];
    }
    float mA, sA; SIM_EPILOGUE(dA, qA, nA, mA, sA);
    float dB[8], qB[8];
#pragma unroll
    for (int r = 0; r < 8; ++r) { dB[r] = dot4(vB[r], k4); qB[r] = dot4(vB[r], vB[r]); }
    BFLY8(dB); BFLY8(qB);
    if (store_nsq) {
#pragma unroll
        for (int r = 0; r < 8; ++r) if (lane == r) ws[OFF_NSQ + nB + r] = qB[r];
    }
    float mB, sB; SIM_EPILOGUE(dB, qB, nB, mB, sB);
    pair_merge(mA, sA, mB, sB);
    block_pair_out(mA, sA, ws, t, lane, wid);
}

// ---- readout (read head hd) fused with next head's write-address sim ----
__global__ __launch_bounds__(256) void k_readout(const float* __restrict__ mem,
                                                 float* __restrict__ ws, int hd,
                                                 int pnext, int use_nsq)
{
    const int t = threadIdx.x, lane = t & 63, wid = t >> 6;
    const float invT = load_invT(ws, t, lane, wid);
    float4 k4 = make_float4(0.f, 0.f, 0.f, 0.f);
    float knorm = 1.f, beta = 0.f;
    if (pnext >= 0) {
        k4    = *(const float4*)(ws + OFF_K + pnext * 256 + lane * 4);
        knorm = ws[OFF_SCAL + pnext * 8 + 0];
        beta  = ws[OFF_SCAL + pnext * 8 + 1];
    }
    const int nA = blockIdx.x * 64 + wid * 16;
    const int nB = nA + 8;
    float wA[8], wB[8]; float4 vA[8], vB[8];
#pragma unroll
    for (int r = 0; r < 8; ++r) wA[r] = ws[OFF_WSH + nA + r];
#pragma unroll
    for (int r = 0; r < 8; ++r) wB[r] = ws[OFF_WSH + nB + r];
#pragma unroll
    for (int r = 0; r < 8; ++r) vA[r] = *(const float4*)(mem + (size_t)(nA + r) * MSZ + lane * 4);
#pragma unroll
    for (int r = 0; r < 8; ++r) vB[r] = *(const float4*)(mem + (size_t)(nB + r) * MSZ + lane * 4);
    float4 acc = make_float4(0.f, 0.f, 0.f, 0.f);
#pragma unroll
    for (int r = 0; r < 8; ++r) {
        const float w = wA[r] * invT;
        acc.x += w * vA[r].x; acc.y += w * vA[r].y;
        acc.z += w * vA[r].z; acc.w += w * vA[r].w;
    }
#pragma unroll
    for (int r = 0; r < 8; ++r) {
        const float w = wB[r] * invT;
        acc.x += w * vB[r].x; acc.y += w * vB[r].y;
        acc.z += w * vB[r].z; acc.w += w * vB[r].w;
    }
    float m = -INFINITY, s = 0.f;
    if (pnext >= 0) {
        float dA[8], qA[8];
#pragma unroll
        for (int r = 0; r < 8; ++r) dA[r] = dot4(vA[r], k4);
        BFLY8(dA);
        if (use_nsq) {
#pragma unroll
            for (int r = 0; r < 8; ++r) qA[r] = ws[OFF_NSQ + nA + r];
        } else {
#pragma unroll
            for (int r = 0; r < 8; ++r) qA[r] = dot4(vA[r], vA[r]);
            BFLY8(qA);
        }
        float mA, sA; SIM_EPILOGUE(dA, qA, nA, mA, sA);
        float dB[8], qB[8];
#pragma unroll
        for (int r = 0; r < 8; ++r) dB[r] = dot4(vB[r], k4);
        BFLY8(dB);
        if (use_nsq) {
#pragma unroll
            for (int r = 0; r < 8; ++r) qB[r] = ws[OFF_NSQ + nB + r];
        } else {
#pragma unroll
            for (int r = 0; r < 8; ++r) qB[r] = dot4(vB[r], vB[r]);
            BFLY8(qB);
        }
        float mB, sB; SIM_EPILOGUE(dB, qB, nB, mB, sB);
        pair_merge(mA, sA, mB, sB);
        m = mA; s = sA;
    }
    __shared__ float lacc[4][256];
    lacc[wid][lane * 4 + 0] = acc.x;
    lacc[wid][lane * 4 + 1] = acc.y;
    lacc[wid][lane * 4 + 2] = acc.z;
    lacc[wid][lane * 4 + 3] = acc.w;
    __syncthreads();
    {
        const float vv = lacc[0][t] + lacc[1][t] + lacc[2][t] + lacc[3][t];
        atomicAdd(ws + OFF_READS + hd * 256 + t, vv);
    }
    if (pnext >= 0) block_pair_out(m, s, ws, t, lane, wid);
}

// ---- output matvec: wave per row (2048 rows) ----
__global__ __launch_bounds__(256) void k_out(const float* __restrict__ W_out,
                                             const float* __restrict__ b_out,
                                             const float* __restrict__ ws,
                                             float* __restrict__ out)
{
    const int row  = (blockIdx.x * 256 + threadIdx.x) >> 6;
    const int lane = threadIdx.x & 63;
    const float* wr    = W_out + (size_t)row * 1024;
    const float* reads = ws + OFF_READS;
    float acc = 0.f;
#pragma unroll
    for (int j = lane * 4; j < 1024; j += 256) {
        acc += dot4(*(const float4*)(wr + j), *(const float4*)(reads + j));
    }
    acc = wave_sum(acc);
    if (lane == 0) out[row] = acc + b_out[row];
}

extern "C" void kernel_launch(void* const* d_in, const int* in_sizes, int n_in,
                              void* d_out, int out_size, void* d_ws, size_t ws_size,
                              hipStream_t stream) {
    (void)in_sizes; (void)n_in; (void)out_size;
    const float* x          = (const float*)d_in[0];
    const float* prev_reads = (const float*)d_in[1];
    const float* prev_h     = (const float*)d_in[2];
    const float* prev_c     = (const float*)d_in[3];
    float*       memory     = (float*)d_in[4];   // updated in place; harness restores per launch
    const float* prev_rw    = (const float*)d_in[5];
    const float* prev_ww    = (const float*)d_in[6];
    const float* W_ih       = (const float*)d_in[7];
    const float* W_hh       = (const float*)d_in[8];
    const float* b_lstm     = (const float*)d_in[9];
    const float* W_out      = (const float*)d_in[10];
    const float* b_out      = (const float*)d_in[11];
    const float* Ww         = (const float*)d_in[12];
    const float* bw         = (const float*)d_in[13];
    const float* Wr         = (const float*)d_in[14];
    const float* br         = (const float*)d_in[15];
    float* out = (float*)d_out;
    float* ws  = (float*)d_ws;
    const int use_nsq = (ws_size >= (size_t)WS_FLOATS * sizeof(float)) ? 1 : 0;

    k_gates <<<1024, 256, 0, stream>>>(x, prev_reads, prev_h, W_ih, W_hh, b_lstm, ws);
    k_cell  <<<4,    256, 0, stream>>>(prev_c, ws);
    k_headfc<<<1036, 256, 0, stream>>>(Ww, bw, Wr, br, ws);
    k_params<<<8,    256, 0, stream>>>(ws);
    k_sim   <<<GRID_BIG, 256, 0, stream>>>(memory, ws, 0);
    for (int hd = 0; hd < 4; ++hd) {
        k_smax   <<<256,      256, 0, stream>>>(prev_ww + (size_t)hd * NMEM, ws, hd);
        k_update <<<GRID_BIG, 256, 0, stream>>>(memory, ws, hd, use_nsq);
        k_smax   <<<256,      256, 0, stream>>>(prev_rw + (size_t)hd * NMEM, ws, 4 + hd);
        k_readout<<<GRID_BIG, 256, 0, stream>>>(memory, ws, hd, (hd < 3) ? (hd + 1) : -1, use_nsq);
    }
    k_out<<<512, 256, 0, stream>>>(W_out, b_out, ws, out);
}